// Round 20
// baseline (475.758 us; speedup 1.0000x reference)
//
#include <hip/hip_runtime.h>
#include <hip/hip_bf16.h>
#include <math.h>

typedef __attribute__((ext_vector_type(8))) short bf16x8;
typedef __attribute__((ext_vector_type(4))) float f32x4;

#define DEVI __device__ __forceinline__

constexpr int B_ = 4, T_ = 1024, C_ = 1024, H_ = 16, HD_ = 64, DI_ = 128;
constexpr int NTOK = B_ * T_;      // 4096
constexpr int C4 = 4 * C_;         // 4096
constexpr int C3 = 3 * C_;         // 3072
constexpr float LAMBDA_CONF = 0.1f;

DEVI short f2bf(float f) {
  unsigned u = __builtin_bit_cast(unsigned, f);
  u += 0x7fffu + ((u >> 16) & 1u);   // RNE
  return (short)(u >> 16);
}
DEVI float bf2f(short s) {
  unsigned u = ((unsigned)(unsigned short)s) << 16;
  return __builtin_bit_cast(float, u);
}
DEVI unsigned pk2(float a, float b) {
  return (unsigned)(unsigned short)f2bf(a) | ((unsigned)(unsigned short)f2bf(b) << 16);
}
DEVI float sigm(float x) { return 1.f / (1.f + __expf(-x)); }
DEVI float geluf(float x) { return 0.5f * x * (1.f + erff(x * 0.70710678118654752440f)); }

DEVI void gload16(const void* g, void* l) {
  __builtin_amdgcn_global_load_lds((const __attribute__((address_space(1))) unsigned*)g,
                                   (__attribute__((address_space(3))) unsigned*)l, 16, 0, 0);
}

// EPI: 0 f32, 1 bf16, 2 bf16(v+bias-0.1*bf16resid), 3 f32(resid+tokv[row]*v),
//      4 bf16 gelu(v+bias), 5 f32(resid+sigm(tokv-1)*(v+bias)), 6 f32(resid+v+bias)
template <int EPI>
DEVI void epi_store(void* Outp, const float* bias, const void* resid, const float* tokv,
                    int row, int col, int N, float v) {
  size_t idx = (size_t)row * N + col;
  if (EPI == 0) {
    ((float*)Outp)[idx] = v;
  } else if (EPI == 1) {
    ((short*)Outp)[idx] = f2bf(v);
  } else if (EPI == 2) {
    ((short*)Outp)[idx] = f2bf(v + bias[col] - LAMBDA_CONF * bf2f(((const short*)resid)[idx]));
  } else if (EPI == 3) {
    ((float*)Outp)[idx] = ((const float*)resid)[idx] + tokv[row] * v;
  } else if (EPI == 4) {
    float x = v + bias[col];
    ((short*)Outp)[idx] = f2bf(geluf(x));
  } else if (EPI == 5) {
    float x = v + bias[col];
    float g = sigm(tokv[row] - 1.f);
    ((float*)Outp)[idx] = ((const float*)resid)[idx] + g * x;
  } else if (EPI == 6) {
    ((float*)Outp)[idx] = ((const float*)resid)[idx] + v + bias[col];
  }
}

// ---------------- weight transpose + f32->bf16 convert: W[K][N] -> Wt[N][K] ----------------
__global__ __launch_bounds__(256) void transpose_cvt(const float* __restrict__ W,
                                                     short* __restrict__ Wt, int K, int N) {
  __shared__ float s[32][33];
  int n0 = blockIdx.x * 32, k0 = blockIdx.y * 32;
  int tx = threadIdx.x & 31, ty = threadIdx.x >> 5;
#pragma unroll
  for (int i = 0; i < 4; i++)
    s[ty + i * 8][tx] = W[(size_t)(k0 + ty + i * 8) * N + n0 + tx];
  __syncthreads();
#pragma unroll
  for (int i = 0; i < 4; i++)
    Wt[(size_t)(n0 + ty + i * 8) * K + k0 + tx] = f2bf(s[tx][ty + i * 8]);
}

// ---------------- V transpose (bf16): QKV V-section [tok][64] -> VT[b][h][64][T] ------------
__global__ __launch_bounds__(256) void transpose_v(const short* __restrict__ QKV,
                                                   short* __restrict__ VT) {
  __shared__ short s[32][33];
  int bh = blockIdx.z;
  int b = bh >> 4, h = bh & 15;
  int t0 = blockIdx.x * 32, d0 = blockIdx.y * 32;
  int tx = threadIdx.x & 31, ty = threadIdx.x >> 5;
#pragma unroll
  for (int i = 0; i < 4; i++)
    s[ty + i * 8][tx] =
        QKV[(size_t)(b * T_ + t0 + ty + i * 8) * C3 + 2 * C_ + h * 64 + d0 + tx];
  __syncthreads();
#pragma unroll
  for (int i = 0; i < 4; i++)
    VT[((size_t)bh * 64 + d0 + ty + i * 8) * T_ + t0 + tx] = s[tx][ty + i * 8];
}

// ---------------- block reduce helper (256 threads) ----------------
DEVI float blk_red(float v, volatile float* sm) {
  int lane = threadIdx.x & 63, wv = threadIdx.x >> 6;
#pragma unroll
  for (int o = 32; o; o >>= 1) v += __shfl_down(v, o);
  __syncthreads();
  if (lane == 0) sm[wv] = v;
  __syncthreads();
  return sm[0] + sm[1] + sm[2] + sm[3];
}

// ---------------- LayerNorm -> bf16 (and optional f32 copy + per-token gates) ----------------
template <int FULL, int WF32>
__global__ __launch_bounds__(256) void ln_kernel(
    const float* __restrict__ X, const float* __restrict__ lnw, const float* __restrict__ lnb,
    float* __restrict__ Out, short* __restrict__ OutBf,
    const float* __restrict__ gw, const float* __restrict__ gb,
    const float* __restrict__ mw, const float* __restrict__ mb,
    const float* __restrict__ ew, const float* __restrict__ eb,
    float* __restrict__ gammaA, float* __restrict__ epsA, float* __restrict__ massA,
    float* __restrict__ coefA, float* __restrict__ hmagA) {
  __shared__ float sm[4];
  int tok = blockIdx.x;
  const float* x = X + (size_t)tok * C_;
  int t4 = threadIdx.x * 4;
  float4 xv = *(const float4*)&x[t4];
  float s = xv.x + xv.y + xv.z + xv.w;
  float ss = xv.x * xv.x + xv.y * xv.y + xv.z * xv.z + xv.w * xv.w;
  s = blk_red(s, sm);
  ss = blk_red(ss, sm);
  float mu = s * (1.f / C_);
  float var = ss * (1.f / C_) - mu * mu;
  float rs = rsqrtf(var + 1e-5f);
  float4 wv = *(const float4*)&lnw[t4];
  float4 bv = *(const float4*)&lnb[t4];
  float4 hn;
  hn.x = (xv.x - mu) * rs * wv.x + bv.x;
  hn.y = (xv.y - mu) * rs * wv.y + bv.y;
  hn.z = (xv.z - mu) * rs * wv.z + bv.z;
  hn.w = (xv.w - mu) * rs * wv.w + bv.w;
  if (WF32) *(float4*)&Out[(size_t)tok * C_ + t4] = hn;
  short4 ob;
  ob.x = f2bf(hn.x); ob.y = f2bf(hn.y); ob.z = f2bf(hn.z); ob.w = f2bf(hn.w);
  *(short4*)&OutBf[(size_t)tok * C_ + t4] = ob;
  if (FULL) {
    float4 gwv = *(const float4*)&gw[t4];
    float4 mwv = *(const float4*)&mw[t4];
    float4 ewv = *(const float4*)&ew[t4];
    float gd = hn.x * gwv.x + hn.y * gwv.y + hn.z * gwv.z + hn.w * gwv.w;
    float md = xv.x * mwv.x + xv.y * mwv.y + xv.z * mwv.z + xv.w * mwv.w;
    float ed = xv.x * ewv.x + xv.y * ewv.y + xv.z * ewv.z + xv.w * ewv.w;
    float h2 = hn.x * hn.x + hn.y * hn.y + hn.z * hn.z + hn.w * hn.w;
    gd = blk_red(gd, sm);
    md = blk_red(md, sm);
    ed = blk_red(ed, sm);
    h2 = blk_red(h2, sm);
    if (threadIdx.x == 0) {
      float g = sigm(gd + gb[0]);
      float xm = md + mb[0];
      float sp = (xm > 20.f) ? xm : log1pf(expf(xm));
      float msv = 1.f + sp;
      float epv = sigm(ed + eb[0]);
      gammaA[tok] = g;
      massA[tok] = msv;
      epsA[tok] = epv;
      coefA[tok] = epv / msv;
      hmagA[tok] = sqrtf(h2);
    }
  }
}

// ---------------- wide-K 8-wave GEMM: 128x128 tile, BK=64, 512 threads ---------------------
// Wave grid 2M x 4N; per-wave output 64x32 (acc[4][2], low VGPR). LDS 32KB -> 4 blocks/CU x
// 8 waves = 32 waves/CU (8/SIMD, max occupancy) on grid-1024 shapes. Same proven 8-slot
// swizzle: phys slot = slot ^ (row&7), inverse-permuted source, read col
// (((kh<<2)|fg)^(fr&7))*8. Single-buffer __syncthreads (race-free).
template <int EPI, int BNFAST>
__global__ __launch_bounds__(512, 4) void gemmW(
    const short* __restrict__ A, const short* __restrict__ Bt, void* __restrict__ Outp,
    const float* __restrict__ bias, const void* __restrict__ resid,
    const float* __restrict__ tokv, int M, int N, int K) {
  __shared__ short As[128][64];
  __shared__ short Bs[128][64];
  int tid = threadIdx.x, lane = tid & 63, w = tid >> 6;  // 8 waves
  int wr = w >> 2, wc = w & 3;                           // 2M x 4N
  int fr = lane & 15, fg = lane >> 4;
  int cpx = gridDim.x >> 3;
  int bid = (blockIdx.x & 7) * cpx + (blockIdx.x >> 3);  // bijective XCD (grid%8==0)
  int bm, bn;
  if constexpr (BNFAST) {
    int nN = N >> 7;
    bn = (bid % nN) << 7;
    bm = (bid / nN) << 7;
  } else {
    int nM = M >> 7;
    bm = (bid % nM) << 7;
    bn = (bid / nM) << 7;
  }
  f32x4 acc[4][2] = {};

  int jsw = (lane & 7) ^ ((lane >> 3) & 7);              // inverse-swizzled source slot
  const short* gA = A + (size_t)(bm + w * 8 + (lane >> 3)) * K + (jsw << 3);
  const short* gB = Bt + (size_t)(bn + w * 8 + (lane >> 3)) * K + (jsw << 3);

  for (int kt = 0; kt < K; kt += 64) {
#pragma unroll
    for (int c = 0; c < 2; c++) {
      gload16(gA + (size_t)(c * 64) * K + kt, &As[c * 64 + w * 8][0]);
      gload16(gB + (size_t)(c * 64) * K + kt, &Bs[c * 64 + w * 8][0]);
    }
    __syncthreads();
#pragma unroll
    for (int kh = 0; kh < 2; kh++) {
      bf16x8 af[4], bv[2];
#pragma unroll
      for (int i = 0; i < 4; i++)
        af[i] = *(const bf16x8*)&As[wr * 64 + i * 16 + fr][(((kh << 2) | fg) ^ (fr & 7)) << 3];
#pragma unroll
      for (int j = 0; j < 2; j++)
        bv[j] = *(const bf16x8*)&Bs[wc * 32 + j * 16 + fr][(((kh << 2) | fg) ^ (fr & 7)) << 3];
#pragma unroll
      for (int mi = 0; mi < 4; mi++)
#pragma unroll
        for (int ni = 0; ni < 2; ni++)
          acc[mi][ni] = __builtin_amdgcn_mfma_f32_16x16x32_bf16(af[mi], bv[ni], acc[mi][ni], 0, 0, 0);
    }
    __syncthreads();
  }

#pragma unroll
  for (int mi = 0; mi < 4; mi++) {
    int row0 = bm + wr * 64 + mi * 16 + fg * 4;
#pragma unroll
    for (int ni = 0; ni < 2; ni++) {
      int col = bn + wc * 32 + ni * 16 + fr;
#pragma unroll
      for (int r = 0; r < 4; r++)
        epi_store<EPI>(Outp, bias, resid, tokv, row0 + r, col, N, acc[mi][ni][r]);
    }
  }
}

// ---------------- 64x64 tile GEMM (r17-proven; lg2/mlp2/wo/V/U) ----------------------------
template <int EPI>
__global__ __launch_bounds__(256, 4) void gemmS64(
    const short* __restrict__ A, const short* __restrict__ Bt, void* __restrict__ Outp,
    const float* __restrict__ bias, const void* __restrict__ resid,
    const float* __restrict__ tokv, int M, int N, int K) {
  __shared__ short As[64][32];
  __shared__ short Bs[64][32];
  int tid = threadIdx.x, lane = tid & 63, w = tid >> 6;
  int wr = w >> 1, wc = w & 1;
  int fr = lane & 15, fg = lane >> 4;
  int xm = (fr >> 1) & 3;
  int cpx = gridDim.x >> 3;
  int bid = (blockIdx.x & 7) * cpx + (blockIdx.x >> 3);  // bijective XCD (grid%8==0)
  int nN = N >> 6;
  int bn = (bid % nN) << 6;   // bn-fast: consecutive bids share bm (A slice L2-resident)
  int bm = (bid / nN) << 6;
  f32x4 acc[2][2] = {};

  int jsw = (lane & 3) ^ ((lane >> 3) & 3);
  const short* gA = A + (size_t)(bm + w * 16 + (lane >> 2)) * K + (jsw << 3);
  const short* gB = Bt + (size_t)(bn + w * 16 + (lane >> 2)) * K + (jsw << 3);

  for (int kt = 0; kt < K; kt += 32) {
    gload16(gA + kt, &As[w * 16][0]);
    gload16(gB + kt, &Bs[w * 16][0]);
    __syncthreads();
    bf16x8 af[2], bv[2];
#pragma unroll
    for (int i = 0; i < 2; i++)
      af[i] = *(const bf16x8*)&As[wr * 32 + i * 16 + fr][(fg ^ xm) << 3];
#pragma unroll
    for (int j = 0; j < 2; j++)
      bv[j] = *(const bf16x8*)&Bs[wc * 32 + j * 16 + fr][(fg ^ xm) << 3];
#pragma unroll
    for (int mi = 0; mi < 2; mi++)
#pragma unroll
      for (int ni = 0; ni < 2; ni++)
        acc[mi][ni] = __builtin_amdgcn_mfma_f32_16x16x32_bf16(af[mi], bv[ni], acc[mi][ni], 0, 0, 0);
    __syncthreads();
  }

#pragma unroll
  for (int mi = 0; mi < 2; mi++) {
    int row0 = bm + wr * 32 + mi * 16 + fg * 4;
#pragma unroll
    for (int ni = 0; ni < 2; ni++) {
      int col = bn + wc * 32 + ni * 16 + fr;
#pragma unroll
      for (int r = 0; r < 4; r++)
        epi_store<EPI>(Outp, bias, resid, tokv, row0 + r, col, N, acc[mi][ni][r]);
    }
  }
}

// ---------------- flash attention v2: KVBLK=64, swizzled gload_lds K/VT, dbuf --------------
__global__ __launch_bounds__(256) void attn_kernel(const short* __restrict__ QKV,
                                                   const short* __restrict__ VT,
                                                   short* __restrict__ Fout) {
  __shared__ short Ks[2][64][64];
  __shared__ short Vts[2][64][64];
  __shared__ short Ps[4][16][72];
  int bh = blockIdx.y;
  int b = bh >> 4, h = bh & 15;
  int qt0 = blockIdx.x * 64;
  int tid = threadIdx.x, lane = tid & 63, w = tid >> 6;
  int fr = lane & 15, fg = lane >> 4;

  size_t base = ((size_t)b * T_) * C3 + h * 64;
  const short* Qp = QKV + base;
  const short* Kp = QKV + base + C_;
  const short* Vtp = VT + (size_t)bh * 64 * T_;
  int qrow = qt0 + w * 16 + fr;
  bf16x8 qf0 = *(const bf16x8*)&Qp[(size_t)qrow * C3 + fg * 8];
  bf16x8 qf1 = *(const bf16x8*)&Qp[(size_t)qrow * C3 + 32 + fg * 8];

  f32x4 oacc[4] = {};
  float m_run = -1e30f, l_run = 0.f;

  int jsw = (lane & 7) ^ ((lane >> 3) & 7);
  int sr8 = w * 8;
  int rsub = lane >> 3;

  auto stage = [&](int buf, int kt) {
#pragma unroll
    for (int c = 0; c < 2; c++) {
      int row = c * 32 + sr8 + rsub;
      gload16(Kp + (size_t)(kt + row) * C3 + jsw * 8, &Ks[buf][c * 32 + sr8][0]);
      gload16(Vtp + (size_t)row * T_ + kt + jsw * 8, &Vts[buf][c * 32 + sr8][0]);
    }
  };

  stage(0, 0);
  for (int t = 0; t < T_ / 64; t++) {
    if (t + 1 < T_ / 64) {
      stage((t + 1) & 1, (t + 1) * 64);
      asm volatile("s_waitcnt vmcnt(4)" ::: "memory");
    } else {
      asm volatile("s_waitcnt vmcnt(0)" ::: "memory");
    }
    __builtin_amdgcn_s_barrier();
    __builtin_amdgcn_sched_barrier(0);
    int cb = t & 1;

    f32x4 sacc[4];
#pragma unroll
    for (int kb = 0; kb < 4; kb++) {
      bf16x8 k0 = *(const bf16x8*)&Ks[cb][kb * 16 + fr][(fg ^ (fr & 7)) << 3];
      bf16x8 k1 = *(const bf16x8*)&Ks[cb][kb * 16 + fr][((4 | fg) ^ (fr & 7)) << 3];
      f32x4 z = {};
      z = __builtin_amdgcn_mfma_f32_16x16x32_bf16(k0, qf0, z, 0, 0, 0);
      z = __builtin_amdgcn_mfma_f32_16x16x32_bf16(k1, qf1, z, 0, 0, 0);
      sacc[kb] = z;
    }
    float mt = -1e30f;
#pragma unroll
    for (int kb = 0; kb < 4; kb++)
#pragma unroll
      for (int r = 0; r < 4; r++) {
        sacc[kb][r] *= 0.125f;
        mt = fmaxf(mt, sacc[kb][r]);
      }
    mt = fmaxf(mt, __shfl_xor(mt, 16));
    mt = fmaxf(mt, __shfl_xor(mt, 32));
    float m_new = fmaxf(m_run, mt);
    float alpha = __expf(m_run - m_new);
    float psum = 0.f;
    float pv[16];
#pragma unroll
    for (int kb = 0; kb < 4; kb++)
#pragma unroll
      for (int r = 0; r < 4; r++) {
        float p = __expf(sacc[kb][r] - m_new);
        pv[kb * 4 + r] = p;
        psum += p;
      }
    psum += __shfl_xor(psum, 16);
    psum += __shfl_xor(psum, 32);
    l_run = l_run * alpha + psum;
    m_run = m_new;

#pragma unroll
    for (int kb = 0; kb < 4; kb++) {
      uint2 pp;
      pp.x = pk2(pv[kb * 4 + 0], pv[kb * 4 + 1]);
      pp.y = pk2(pv[kb * 4 + 2], pv[kb * 4 + 3]);
      *(uint2*)&Ps[w][fr][kb * 16 + fg * 4] = pp;
    }
    float ar[4];
#pragma unroll
    for (int r = 0; r < 4; r++) ar[r] = __shfl(alpha, fg * 4 + r);
#pragma unroll
    for (int ni = 0; ni < 4; ni++)
#pragma unroll
      for (int r = 0; r < 4; r++) oacc[ni][r] *= ar[r];

    asm volatile("s_waitcnt lgkmcnt(0)" ::: "memory");
    __builtin_amdgcn_sched_barrier(0);
    bf16x8 pa0 = *(const bf16x8*)&Ps[w][fr][fg * 8];
    bf16x8 pa1 = *(const bf16x8*)&Ps[w][fr][32 + fg * 8];
#pragma unroll
    for (int ni = 0; ni < 4; ni++) {
      bf16x8 v0 = *(const bf16x8*)&Vts[cb][ni * 16 + fr][(fg ^ (fr & 7)) << 3];
      bf16x8 v1 = *(const bf16x8*)&Vts[cb][ni * 16 + fr][((4 | fg) ^ (fr & 7)) << 3];
      oacc[ni] = __builtin_amdgcn_mfma_f32_16x16x32_bf16(pa0, v0, oacc[ni], 0, 0, 0);
      oacc[ni] = __builtin_amdgcn_mfma_f32_16x16x32_bf16(pa1, v1, oacc[ni], 0, 0, 0);
    }
    __builtin_amdgcn_sched_barrier(0);   // pin PV reads above the barrier (dbuf safety)
    __builtin_amdgcn_s_barrier();
  }

  float lr4[4];
#pragma unroll
  for (int r = 0; r < 4; r++) lr4[r] = __shfl(l_run, fg * 4 + r);
#pragma unroll
  for (int ni = 0; ni < 4; ni++)
#pragma unroll
    for (int r = 0; r < 4; r++) {
      int tok = b * T_ + qt0 + w * 16 + fg * 4 + r;
      Fout[(size_t)tok * C_ + h * 64 + ni * 16 + fr] = f2bf(oacc[ni][r] / lr4[r]);
    }
}

// ---------------- sequential momentum scan ----------------
__global__ __launch_bounds__(128) void scan_kernel(const float* __restrict__ f_proj,
                                                   const float* __restrict__ gam,
                                                   const float* __restrict__ coef,
                                                   float* __restrict__ m_out,
                                                   short* __restrict__ m_bf) {
  int b = blockIdx.x;
  int d = threadIdx.x;
  const float* fp = f_proj + (size_t)b * T_ * DI_ + d;
  const float* g = gam + (size_t)b * T_;
  const float* c = coef + (size_t)b * T_;
  float* mo = m_out + (size_t)b * T_ * DI_ + d;
  short* mb = m_bf + (size_t)b * T_ * DI_ + d;
  float m = 0.f;
  for (int t = 0; t < T_; t += 8) {
    float fv[8], gv[8], cv[8];
#pragma unroll
    for (int i = 0; i < 8; i++) {
      fv[i] = fp[(size_t)(t + i) * DI_];
      gv[i] = g[t + i];
      cv[i] = c[t + i];
    }
#pragma unroll
    for (int i = 0; i < 8; i++) {
      m = gv[i] * m + cv[i] * fv[i];
      mo[(size_t)(t + i) * DI_] = m;
      mb[(size_t)(t + i) * DI_] = f2bf(m);
    }
  }
}

// ---------------- fsi ----------------
__global__ __launch_bounds__(256) void fsi_kernel(const float* __restrict__ f_proj,
                                                  const float* __restrict__ hmag,
                                                  float* __restrict__ fsi_out) {
  int tok = blockIdx.x * 4 + (threadIdx.x >> 6);
  int l = threadIdx.x & 63;
  float2 v = *(const float2*)&f_proj[(size_t)tok * DI_ + l * 2];
  float s = v.x * v.x + v.y * v.y;
#pragma unroll
  for (int o = 32; o; o >>= 1) s += __shfl_down(s, o);
  if (l == 0) fsi_out[tok] = hmag[tok] / (2.f * sqrtf(s) + 1e-6f);
}

// ---------------- launcher ----------------
extern "C" void kernel_launch(void* const* d_in, const int* in_sizes, int n_in,
                              void* d_out, int out_size, void* d_ws, size_t ws_size,
                              hipStream_t stream) {
  (void)in_sizes; (void)n_in; (void)out_size; (void)ws_size;
  const float* h = (const float*)d_in[0];
  const float* ln_w = (const float*)d_in[1];
  const float* ln_b = (const float*)d_in[2];
  const float* w_q = (const float*)d_in[3];
  const float* w_k = (const float*)d_in[4];
  const float* w_v = (const float*)d_in[5];
  const float* w_o = (const float*)d_in[6];
  const float* b_o = (const float*)d_in[7];
  const float* U = (const float*)d_in[8];
  const float* V = (const float*)d_in[9];
  const float* gamma_w = (const float*)d_in[10];
  const float* gamma_b = (const float*)d_in[11];
  const float* mass_w = (const float*)d_in[12];
  const float* mass_b = (const float*)d_in[13];
  const float* eps_w = (const float*)d_in[14];
  const float* eps_b = (const float*)d_in[15];
  const float* lg_w1 = (const float*)d_in[16];
  const float* lg_b1 = (const float*)d_in[17];
  const float* lg_w2 = (const float*)d_in[18];
  const float* lg_b2 = (const float*)d_in[19];
  const float* mlp_w1 = (const float*)d_in[20];
  const float* mlp_b1 = (const float*)d_in[21];
  const float* mlp_w2 = (const float*)d_in[22];
  const float* mlp_b2 = (const float*)d_in[23];

  float* out_h = (float*)d_out;
  float* out_m = out_h + (size_t)NTOK * C_;
  float* out_fsi = out_m + (size_t)NTOK * DI_;

  char* wsb = (char*)d_ws;
  size_t off = 0;
  auto al = [&](size_t bytes) {
    void* p = wsb + off;
    off += (bytes + 255) & ~(size_t)255;
    return p;
  };
  short* wqkvt = (short*)al((size_t)C3 * C_ * 2);
  short* wot = (short*)al((size_t)C_ * C_ * 2);
  short* ut = (short*)al((size_t)DI_ * C_ * 2);
  short* vt = (short*)al((size_t)C_ * DI_ * 2);
  short* lg1t = (short*)al((size_t)C4 * C_ * 2);
  short* lg2t = (short*)al((size_t)C_ * C4 * 2);
  short* mlp1t = (short*)al((size_t)C4 * C_ * 2);
  short* mlp2t = (short*)al((size_t)C_ * C4 * 2);
  short* hn_bf = (short*)al((size_t)NTOK * C_ * 2);
  short* qkv_bf = (short*)al((size_t)NTOK * C3 * 2);
  short* tmp_bf = (short*)al((size_t)NTOK * C_ * 2);
  float* f_proj = (float*)al((size_t)NTOK * DI_ * 4);
  short* act = (short*)al((size_t)NTOK * C4 * 2);
  float* h_pre = (float*)al((size_t)NTOK * C_ * 4);
  short* vtrans = (short*)al((size_t)B_ * H_ * 64 * T_ * 2);
  float* gammaA = (float*)al((size_t)NTOK * 4);
  float* epsA = (float*)al((size_t)NTOK * 4);
  float* massA = (float*)al((size_t)NTOK * 4);
  float* coefA = (float*)al((size_t)NTOK * 4);
  float* hmagA = (float*)al((size_t)NTOK * 4);
  short* ftot_bf = hn_bf;   // overlay: f_total overwrites hn_bf after wo (read==write idx, safe)
  short* m_bf = act;
  float* h_new = (float*)qkv_bf;

  dim3 blk(256);
  dim3 blk512(512);
  transpose_cvt<<<dim3(C_ / 32, C_ / 32), blk, 0, stream>>>(w_q, wqkvt, C_, C_);
  transpose_cvt<<<dim3(C_ / 32, C_ / 32), blk, 0, stream>>>(w_k, wqkvt + (size_t)C_ * C_, C_, C_);
  transpose_cvt<<<dim3(C_ / 32, C_ / 32), blk, 0, stream>>>(w_v, wqkvt + (size_t)2 * C_ * C_, C_, C_);
  transpose_cvt<<<dim3(C_ / 32, C_ / 32), blk, 0, stream>>>(w_o, wot, C_, C_);
  transpose_cvt<<<dim3(DI_ / 32, C_ / 32), blk, 0, stream>>>(U, ut, C_, DI_);
  transpose_cvt<<<dim3(C_ / 32, DI_ / 32), blk, 0, stream>>>(V, vt, DI_, C_);
  transpose_cvt<<<dim3(C4 / 32, C_ / 32), blk, 0, stream>>>(lg_w1, lg1t, C_, C4);
  transpose_cvt<<<dim3(C_ / 32, C4 / 32), blk, 0, stream>>>(lg_w2, lg2t, C4, C_);
  transpose_cvt<<<dim3(C4 / 32, C_ / 32), blk, 0, stream>>>(mlp_w1, mlp1t, C_, C4);
  transpose_cvt<<<dim3(C_ / 32, C4 / 32), blk, 0, stream>>>(mlp_w2, mlp2t, C4, C_);

  // LN1 + gates (bf16 only; f32 h_norm dropped - EPI2 residual reads bf16)
  ln_kernel<1, 0><<<NTOK, blk, 0, stream>>>(h, ln_w, ln_b, nullptr, hn_bf, gamma_w, gamma_b,
                                            mass_w, mass_b, eps_w, eps_b, gammaA, epsA, massA,
                                            coefA, hmagA);
  // fused QKV: 8-wave wide-K, grid 768
  gemmW<1, 0><<<(NTOK / 128) * (C3 / 128), blk512, 0, stream>>>(hn_bf, wqkvt, qkv_bf, nullptr,
                                                                nullptr, nullptr, NTOK, C3, C_);
  transpose_v<<<dim3(T_ / 32, 2, B_ * H_), blk, 0, stream>>>(qkv_bf, vtrans);
  attn_kernel<<<dim3(T_ / 64, B_ * H_), blk, 0, stream>>>(qkv_bf, vtrans, tmp_bf);
  // wo: 64x64, grid 1024; resid = hn_bf (bf16), output overwrites hn_bf in-place (same idx)
  gemmS64<2><<<(NTOK / 64) * (C_ / 64), blk, 0, stream>>>(tmp_bf, wot, ftot_bf, b_o,
                                                          hn_bf, nullptr, NTOK, C_, C_);
  // U: 64x64, grid 128
  gemmS64<0><<<(NTOK / 64) * (DI_ / 64), blk, 0, stream>>>(ftot_bf, ut, f_proj, nullptr,
                                                           nullptr, nullptr, NTOK, DI_, C_);
  fsi_kernel<<<NTOK / 4, blk, 0, stream>>>(f_proj, hmagA, out_fsi);
  scan_kernel<<<B_, dim3(DI_), 0, stream>>>(f_proj, gammaA, coefA, out_m, m_bf);
  // V-gemm: 64x64, grid 1024 (K=128); resid = h (f32)
  gemmS64<3><<<(NTOK / 64) * (C_ / 64), blk, 0, stream>>>(m_bf, vt, h_new, nullptr, h,
                                                          epsA, NTOK, C_, DI_);
  ln_kernel<0, 0><<<NTOK, blk, 0, stream>>>(h_new, ln_w, ln_b, nullptr, tmp_bf, nullptr, nullptr,
                                            nullptr, nullptr, nullptr, nullptr, nullptr, nullptr,
                                            nullptr, nullptr, nullptr);
  // lg1: 8-wave wide-K, grid 1024
  gemmW<4, 0><<<(NTOK / 128) * (C4 / 128), blk512, 0, stream>>>(tmp_bf, lg1t, act, lg_b1,
                                                                nullptr, nullptr, NTOK, C4, C_);
  // lg2: 64x64, grid 1024; resid = h_new (f32)
  gemmS64<5><<<(NTOK / 64) * (C_ / 64), blk, 0, stream>>>(act, lg2t, h_pre, lg_b2,
                                                          h_new, massA, NTOK, C_, C4);
  ln_kernel<0, 0><<<NTOK, blk, 0, stream>>>(h_pre, ln_w, ln_b, nullptr, tmp_bf, nullptr, nullptr,
                                            nullptr, nullptr, nullptr, nullptr, nullptr, nullptr,
                                            nullptr, nullptr, nullptr);
  gemmW<4, 0><<<(NTOK / 128) * (C4 / 128), blk512, 0, stream>>>(tmp_bf, mlp1t, act, mlp_b1,
                                                                nullptr, nullptr, NTOK, C4, C_);
  gemmS64<6><<<(NTOK / 64) * (C_ / 64), blk, 0, stream>>>(act, mlp2t, out_h, mlp_b2,
                                                          h_pre, nullptr, NTOK, C_, C4);
}

// Round 21
// 467.880 us; speedup vs baseline: 1.0168x; 1.0168x over previous
//
#include <hip/hip_runtime.h>
#include <hip/hip_bf16.h>
#include <math.h>

typedef __attribute__((ext_vector_type(8))) short bf16x8;
typedef __attribute__((ext_vector_type(4))) float f32x4;

#define DEVI __device__ __forceinline__

constexpr int B_ = 4, T_ = 1024, C_ = 1024, H_ = 16, HD_ = 64, DI_ = 128;
constexpr int NTOK = B_ * T_;      // 4096
constexpr int C4 = 4 * C_;         // 4096
constexpr int C3 = 3 * C_;         // 3072
constexpr float LAMBDA_CONF = 0.1f;

DEVI short f2bf(float f) {
  unsigned u = __builtin_bit_cast(unsigned, f);
  u += 0x7fffu + ((u >> 16) & 1u);   // RNE
  return (short)(u >> 16);
}
DEVI unsigned pk2(float a, float b) {
  return (unsigned)(unsigned short)f2bf(a) | ((unsigned)(unsigned short)f2bf(b) << 16);
}
DEVI float sigm(float x) { return 1.f / (1.f + __expf(-x)); }
DEVI float geluf(float x) { return 0.5f * x * (1.f + erff(x * 0.70710678118654752440f)); }

DEVI void gload16(const void* g, void* l) {
  __builtin_amdgcn_global_load_lds((const __attribute__((address_space(1))) unsigned*)g,
                                   (__attribute__((address_space(3))) unsigned*)l, 16, 0, 0);
}

template <int EPI>
DEVI void epi_store(void* Outp, const float* bias, const float* resid, const float* tokv,
                    int row, int col, int N, float v) {
  size_t idx = (size_t)row * N + col;
  if (EPI == 0) {
    ((float*)Outp)[idx] = v;
  } else if (EPI == 1) {
    ((short*)Outp)[idx] = f2bf(v);
  } else if (EPI == 2) {
    ((short*)Outp)[idx] = f2bf(v + bias[col] - LAMBDA_CONF * resid[idx]);
  } else if (EPI == 3) {
    ((float*)Outp)[idx] = resid[idx] + tokv[row] * v;
  } else if (EPI == 4) {
    float x = v + bias[col];
    ((short*)Outp)[idx] = f2bf(geluf(x));
  } else if (EPI == 5) {
    float x = v + bias[col];
    float g = sigm(tokv[row] - 1.f);
    ((float*)Outp)[idx] = resid[idx] + g * x;
  } else if (EPI == 6) {
    ((float*)Outp)[idx] = resid[idx] + v + bias[col];
  }
}

// ---------------- weight transpose + f32->bf16 convert: W[K][N] -> Wt[N][K] ----------------
__global__ __launch_bounds__(256) void transpose_cvt(const float* __restrict__ W,
                                                     short* __restrict__ Wt, int K, int N) {
  __shared__ float s[32][33];
  int n0 = blockIdx.x * 32, k0 = blockIdx.y * 32;
  int tx = threadIdx.x & 31, ty = threadIdx.x >> 5;
#pragma unroll
  for (int i = 0; i < 4; i++)
    s[ty + i * 8][tx] = W[(size_t)(k0 + ty + i * 8) * N + n0 + tx];
  __syncthreads();
#pragma unroll
  for (int i = 0; i < 4; i++)
    Wt[(size_t)(n0 + ty + i * 8) * K + k0 + tx] = f2bf(s[tx][ty + i * 8]);
}

// ---------------- V transpose (bf16): QKV V-section [tok][64] -> VT[b][h][64][T] ------------
__global__ __launch_bounds__(256) void transpose_v(const short* __restrict__ QKV,
                                                   short* __restrict__ VT) {
  __shared__ short s[32][33];
  int bh = blockIdx.z;
  int b = bh >> 4, h = bh & 15;
  int t0 = blockIdx.x * 32, d0 = blockIdx.y * 32;
  int tx = threadIdx.x & 31, ty = threadIdx.x >> 5;
#pragma unroll
  for (int i = 0; i < 4; i++)
    s[ty + i * 8][tx] =
        QKV[(size_t)(b * T_ + t0 + ty + i * 8) * C3 + 2 * C_ + h * 64 + d0 + tx];
  __syncthreads();
#pragma unroll
  for (int i = 0; i < 4; i++)
    VT[((size_t)bh * 64 + d0 + ty + i * 8) * T_ + t0 + tx] = s[tx][ty + i * 8];
}

// ---------------- block reduce helper (256 threads) ----------------
DEVI float blk_red(float v, volatile float* sm) {
  int lane = threadIdx.x & 63, wv = threadIdx.x >> 6;
#pragma unroll
  for (int o = 32; o; o >>= 1) v += __shfl_down(v, o);
  __syncthreads();
  if (lane == 0) sm[wv] = v;
  __syncthreads();
  return sm[0] + sm[1] + sm[2] + sm[3];
}

// ---------------- LayerNorm -> bf16 (and optional f32 copy + per-token gates) ----------------
template <int FULL, int WF32>
__global__ __launch_bounds__(256) void ln_kernel(
    const float* __restrict__ X, const float* __restrict__ lnw, const float* __restrict__ lnb,
    float* __restrict__ Out, short* __restrict__ OutBf,
    const float* __restrict__ gw, const float* __restrict__ gb,
    const float* __restrict__ mw, const float* __restrict__ mb,
    const float* __restrict__ ew, const float* __restrict__ eb,
    float* __restrict__ gammaA, float* __restrict__ epsA, float* __restrict__ massA,
    float* __restrict__ coefA, float* __restrict__ hmagA) {
  __shared__ float sm[4];
  int tok = blockIdx.x;
  const float* x = X + (size_t)tok * C_;
  int t4 = threadIdx.x * 4;
  float4 xv = *(const float4*)&x[t4];
  float s = xv.x + xv.y + xv.z + xv.w;
  float ss = xv.x * xv.x + xv.y * xv.y + xv.z * xv.z + xv.w * xv.w;
  s = blk_red(s, sm);
  ss = blk_red(ss, sm);
  float mu = s * (1.f / C_);
  float var = ss * (1.f / C_) - mu * mu;
  float rs = rsqrtf(var + 1e-5f);
  float4 wv = *(const float4*)&lnw[t4];
  float4 bv = *(const float4*)&lnb[t4];
  float4 hn;
  hn.x = (xv.x - mu) * rs * wv.x + bv.x;
  hn.y = (xv.y - mu) * rs * wv.y + bv.y;
  hn.z = (xv.z - mu) * rs * wv.z + bv.z;
  hn.w = (xv.w - mu) * rs * wv.w + bv.w;
  if (WF32) *(float4*)&Out[(size_t)tok * C_ + t4] = hn;
  short4 ob;
  ob.x = f2bf(hn.x); ob.y = f2bf(hn.y); ob.z = f2bf(hn.z); ob.w = f2bf(hn.w);
  *(short4*)&OutBf[(size_t)tok * C_ + t4] = ob;
  if (FULL) {
    float4 gwv = *(const float4*)&gw[t4];
    float4 mwv = *(const float4*)&mw[t4];
    float4 ewv = *(const float4*)&ew[t4];
    float gd = hn.x * gwv.x + hn.y * gwv.y + hn.z * gwv.z + hn.w * gwv.w;
    float md = xv.x * mwv.x + xv.y * mwv.y + xv.z * mwv.z + xv.w * mwv.w;
    float ed = xv.x * ewv.x + xv.y * ewv.y + xv.z * ewv.z + xv.w * ewv.w;
    float h2 = hn.x * hn.x + hn.y * hn.y + hn.z * hn.z + hn.w * hn.w;
    gd = blk_red(gd, sm);
    md = blk_red(md, sm);
    ed = blk_red(ed, sm);
    h2 = blk_red(h2, sm);
    if (threadIdx.x == 0) {
      float g = sigm(gd + gb[0]);
      float xm = md + mb[0];
      float sp = (xm > 20.f) ? xm : log1pf(expf(xm));
      float msv = 1.f + sp;
      float epv = sigm(ed + eb[0]);
      gammaA[tok] = g;
      massA[tok] = msv;
      epsA[tok] = epv;
      coefA[tok] = epv / msv;
      hmagA[tok] = sqrtf(h2);
    }
  }
}

// ---------------- wide-K single-buffer GEMM: 128x128 tile, BK=64, 4 waves ------------------
// LDS 32KB -> 4 blocks/CU (launch_bounds(256,4)); half the barriers/drains of BK=32 (16 vs
// 32 K-steps), 32 MFMA per step. Staging/read = proven 8-slot swizzle (row stride 128B):
// phys slot = slot ^ (row&7), inverse-permuted global source. __syncthreads both sides
// (full memory barrier -> race-free single buffer). r19-verified best: 468.0 us total.
template <int EPI, int BNFAST>
__global__ __launch_bounds__(256, 4) void gemmW(
    const short* __restrict__ A, const short* __restrict__ Bt, void* __restrict__ Outp,
    const float* __restrict__ bias, const float* __restrict__ resid,
    const float* __restrict__ tokv, int M, int N, int K) {
  __shared__ short As[128][64];
  __shared__ short Bs[128][64];
  int tid = threadIdx.x, lane = tid & 63, w = tid >> 6;  // 4 waves
  int wr = w >> 1, wc = w & 1;
  int fr = lane & 15, fg = lane >> 4;
  int cpx = gridDim.x >> 3;
  int bid = (blockIdx.x & 7) * cpx + (blockIdx.x >> 3);  // bijective XCD (grid%8==0)
  int bm, bn;
  if constexpr (BNFAST) {
    int nN = N >> 7;
    bn = (bid % nN) << 7;
    bm = (bid / nN) << 7;
  } else {
    int nM = M >> 7;
    bm = (bid % nM) << 7;
    bn = (bid / nM) << 7;
  }
  f32x4 acc[4][4] = {};

  int jsw = (lane & 7) ^ ((lane >> 3) & 7);              // inverse-swizzled source slot
  const short* gA = A + (size_t)(bm + w * 8 + (lane >> 3)) * K + (jsw << 3);
  const short* gB = Bt + (size_t)(bn + w * 8 + (lane >> 3)) * K + (jsw << 3);

  for (int kt = 0; kt < K; kt += 64) {
#pragma unroll
    for (int c = 0; c < 4; c++)
      gload16(gA + (size_t)(c * 32) * K + kt, &As[c * 32 + w * 8][0]);
#pragma unroll
    for (int c = 0; c < 4; c++)
      gload16(gB + (size_t)(c * 32) * K + kt, &Bs[c * 32 + w * 8][0]);
    __syncthreads();
#pragma unroll
    for (int kh = 0; kh < 2; kh++) {
      bf16x8 af[4], bv[4];
#pragma unroll
      for (int i = 0; i < 4; i++)
        af[i] = *(const bf16x8*)&As[wr * 64 + i * 16 + fr][(((kh << 2) | fg) ^ (fr & 7)) << 3];
#pragma unroll
      for (int j = 0; j < 4; j++)
        bv[j] = *(const bf16x8*)&Bs[wc * 64 + j * 16 + fr][(((kh << 2) | fg) ^ (fr & 7)) << 3];
#pragma unroll
      for (int mi = 0; mi < 4; mi++)
#pragma unroll
        for (int ni = 0; ni < 4; ni++)
          acc[mi][ni] = __builtin_amdgcn_mfma_f32_16x16x32_bf16(af[mi], bv[ni], acc[mi][ni], 0, 0, 0);
    }
    __syncthreads();
  }

#pragma unroll
  for (int mi = 0; mi < 4; mi++) {
    int row0 = bm + wr * 64 + mi * 16 + fg * 4;
#pragma unroll
    for (int ni = 0; ni < 4; ni++) {
      int col = bn + wc * 64 + ni * 16 + fr;
#pragma unroll
      for (int r = 0; r < 4; r++)
        epi_store<EPI>(Outp, bias, resid, tokv, row0 + r, col, N, acc[mi][ni][r]);
    }
  }
}

// ---------------- 64x64 tile GEMM (r17-proven; lg2/mlp2/wo/V/U) ----------------------------
template <int EPI>
__global__ __launch_bounds__(256, 4) void gemmS64(
    const short* __restrict__ A, const short* __restrict__ Bt, void* __restrict__ Outp,
    const float* __restrict__ bias, const float* __restrict__ resid,
    const float* __restrict__ tokv, int M, int N, int K) {
  __shared__ short As[64][32];
  __shared__ short Bs[64][32];
  int tid = threadIdx.x, lane = tid & 63, w = tid >> 6;
  int wr = w >> 1, wc = w & 1;
  int fr = lane & 15, fg = lane >> 4;
  int xm = (fr >> 1) & 3;
  int cpx = gridDim.x >> 3;
  int bid = (blockIdx.x & 7) * cpx + (blockIdx.x >> 3);  // bijective XCD (grid%8==0)
  int nN = N >> 6;
  int bn = (bid % nN) << 6;   // bn-fast: consecutive bids share bm (A slice L2-resident)
  int bm = (bid / nN) << 6;
  f32x4 acc[2][2] = {};

  int jsw = (lane & 3) ^ ((lane >> 3) & 3);
  const short* gA = A + (size_t)(bm + w * 16 + (lane >> 2)) * K + (jsw << 3);
  const short* gB = Bt + (size_t)(bn + w * 16 + (lane >> 2)) * K + (jsw << 3);

  for (int kt = 0; kt < K; kt += 32) {
    gload16(gA + kt, &As[w * 16][0]);
    gload16(gB + kt, &Bs[w * 16][0]);
    __syncthreads();
    bf16x8 af[2], bv[2];
#pragma unroll
    for (int i = 0; i < 2; i++)
      af[i] = *(const bf16x8*)&As[wr * 32 + i * 16 + fr][(fg ^ xm) << 3];
#pragma unroll
    for (int j = 0; j < 2; j++)
      bv[j] = *(const bf16x8*)&Bs[wc * 32 + j * 16 + fr][(fg ^ xm) << 3];
#pragma unroll
    for (int mi = 0; mi < 2; mi++)
#pragma unroll
      for (int ni = 0; ni < 2; ni++)
        acc[mi][ni] = __builtin_amdgcn_mfma_f32_16x16x32_bf16(af[mi], bv[ni], acc[mi][ni], 0, 0, 0);
    __syncthreads();
  }

#pragma unroll
  for (int mi = 0; mi < 2; mi++) {
    int row0 = bm + wr * 32 + mi * 16 + fg * 4;
#pragma unroll
    for (int ni = 0; ni < 2; ni++) {
      int col = bn + wc * 32 + ni * 16 + fr;
#pragma unroll
      for (int r = 0; r < 4; r++)
        epi_store<EPI>(Outp, bias, resid, tokv, row0 + r, col, N, acc[mi][ni][r]);
    }
  }
}

// ---------------- flash attention v2: KVBLK=64, swizzled gload_lds K/VT, dbuf --------------
__global__ __launch_bounds__(256) void attn_kernel(const short* __restrict__ QKV,
                                                   const short* __restrict__ VT,
                                                   short* __restrict__ Fout) {
  __shared__ short Ks[2][64][64];
  __shared__ short Vts[2][64][64];
  __shared__ short Ps[4][16][72];
  int bh = blockIdx.y;
  int b = bh >> 4, h = bh & 15;
  int qt0 = blockIdx.x * 64;
  int tid = threadIdx.x, lane = tid & 63, w = tid >> 6;
  int fr = lane & 15, fg = lane >> 4;

  size_t base = ((size_t)b * T_) * C3 + h * 64;
  const short* Qp = QKV + base;
  const short* Kp = QKV + base + C_;
  const short* Vtp = VT + (size_t)bh * 64 * T_;
  int qrow = qt0 + w * 16 + fr;
  bf16x8 qf0 = *(const bf16x8*)&Qp[(size_t)qrow * C3 + fg * 8];
  bf16x8 qf1 = *(const bf16x8*)&Qp[(size_t)qrow * C3 + 32 + fg * 8];

  f32x4 oacc[4] = {};
  float m_run = -1e30f, l_run = 0.f;

  int jsw = (lane & 7) ^ ((lane >> 3) & 7);
  int sr8 = w * 8;
  int rsub = lane >> 3;

  auto stage = [&](int buf, int kt) {
#pragma unroll
    for (int c = 0; c < 2; c++) {
      int row = c * 32 + sr8 + rsub;
      gload16(Kp + (size_t)(kt + row) * C3 + jsw * 8, &Ks[buf][c * 32 + sr8][0]);
      gload16(Vtp + (size_t)row * T_ + kt + jsw * 8, &Vts[buf][c * 32 + sr8][0]);
    }
  };

  stage(0, 0);
  for (int t = 0; t < T_ / 64; t++) {
    if (t + 1 < T_ / 64) {
      stage((t + 1) & 1, (t + 1) * 64);
      asm volatile("s_waitcnt vmcnt(4)" ::: "memory");
    } else {
      asm volatile("s_waitcnt vmcnt(0)" ::: "memory");
    }
    __builtin_amdgcn_s_barrier();
    __builtin_amdgcn_sched_barrier(0);
    int cb = t & 1;

    f32x4 sacc[4];
#pragma unroll
    for (int kb = 0; kb < 4; kb++) {
      bf16x8 k0 = *(const bf16x8*)&Ks[cb][kb * 16 + fr][(fg ^ (fr & 7)) << 3];
      bf16x8 k1 = *(const bf16x8*)&Ks[cb][kb * 16 + fr][((4 | fg) ^ (fr & 7)) << 3];
      f32x4 z = {};
      z = __builtin_amdgcn_mfma_f32_16x16x32_bf16(k0, qf0, z, 0, 0, 0);
      z = __builtin_amdgcn_mfma_f32_16x16x32_bf16(k1, qf1, z, 0, 0, 0);
      sacc[kb] = z;
    }
    float mt = -1e30f;
#pragma unroll
    for (int kb = 0; kb < 4; kb++)
#pragma unroll
      for (int r = 0; r < 4; r++) {
        sacc[kb][r] *= 0.125f;
        mt = fmaxf(mt, sacc[kb][r]);
      }
    mt = fmaxf(mt, __shfl_xor(mt, 16));
    mt = fmaxf(mt, __shfl_xor(mt, 32));
    float m_new = fmaxf(m_run, mt);
    float alpha = __expf(m_run - m_new);
    float psum = 0.f;
    float pv[16];
#pragma unroll
    for (int kb = 0; kb < 4; kb++)
#pragma unroll
      for (int r = 0; r < 4; r++) {
        float p = __expf(sacc[kb][r] - m_new);
        pv[kb * 4 + r] = p;
        psum += p;
      }
    psum += __shfl_xor(psum, 16);
    psum += __shfl_xor(psum, 32);
    l_run = l_run * alpha + psum;
    m_run = m_new;

#pragma unroll
    for (int kb = 0; kb < 4; kb++) {
      uint2 pp;
      pp.x = pk2(pv[kb * 4 + 0], pv[kb * 4 + 1]);
      pp.y = pk2(pv[kb * 4 + 2], pv[kb * 4 + 3]);
      *(uint2*)&Ps[w][fr][kb * 16 + fg * 4] = pp;
    }
    float ar[4];
#pragma unroll
    for (int r = 0; r < 4; r++) ar[r] = __shfl(alpha, fg * 4 + r);
#pragma unroll
    for (int ni = 0; ni < 4; ni++)
#pragma unroll
      for (int r = 0; r < 4; r++) oacc[ni][r] *= ar[r];

    asm volatile("s_waitcnt lgkmcnt(0)" ::: "memory");
    __builtin_amdgcn_sched_barrier(0);
    bf16x8 pa0 = *(const bf16x8*)&Ps[w][fr][fg * 8];
    bf16x8 pa1 = *(const bf16x8*)&Ps[w][fr][32 + fg * 8];
#pragma unroll
    for (int ni = 0; ni < 4; ni++) {
      bf16x8 v0 = *(const bf16x8*)&Vts[cb][ni * 16 + fr][(fg ^ (fr & 7)) << 3];
      bf16x8 v1 = *(const bf16x8*)&Vts[cb][ni * 16 + fr][((4 | fg) ^ (fr & 7)) << 3];
      oacc[ni] = __builtin_amdgcn_mfma_f32_16x16x32_bf16(pa0, v0, oacc[ni], 0, 0, 0);
      oacc[ni] = __builtin_amdgcn_mfma_f32_16x16x32_bf16(pa1, v1, oacc[ni], 0, 0, 0);
    }
    __builtin_amdgcn_sched_barrier(0);   // pin PV reads above the barrier (dbuf safety)
    __builtin_amdgcn_s_barrier();
  }

  float lr4[4];
#pragma unroll
  for (int r = 0; r < 4; r++) lr4[r] = __shfl(l_run, fg * 4 + r);
#pragma unroll
  for (int ni = 0; ni < 4; ni++)
#pragma unroll
    for (int r = 0; r < 4; r++) {
      int tok = b * T_ + qt0 + w * 16 + fg * 4 + r;
      Fout[(size_t)tok * C_ + h * 64 + ni * 16 + fr] = f2bf(oacc[ni][r] / lr4[r]);
    }
}

// ---------------- sequential momentum scan ----------------
__global__ __launch_bounds__(128) void scan_kernel(const float* __restrict__ f_proj,
                                                   const float* __restrict__ gam,
                                                   const float* __restrict__ coef,
                                                   float* __restrict__ m_out,
                                                   short* __restrict__ m_bf) {
  int b = blockIdx.x;
  int d = threadIdx.x;
  const float* fp = f_proj + (size_t)b * T_ * DI_ + d;
  const float* g = gam + (size_t)b * T_;
  const float* c = coef + (size_t)b * T_;
  float* mo = m_out + (size_t)b * T_ * DI_ + d;
  short* mb = m_bf + (size_t)b * T_ * DI_ + d;
  float m = 0.f;
  for (int t = 0; t < T_; t += 8) {
    float fv[8], gv[8], cv[8];
#pragma unroll
    for (int i = 0; i < 8; i++) {
      fv[i] = fp[(size_t)(t + i) * DI_];
      gv[i] = g[t + i];
      cv[i] = c[t + i];
    }
#pragma unroll
    for (int i = 0; i < 8; i++) {
      m = gv[i] * m + cv[i] * fv[i];
      mo[(size_t)(t + i) * DI_] = m;
      mb[(size_t)(t + i) * DI_] = f2bf(m);
    }
  }
}

// ---------------- fsi ----------------
__global__ __launch_bounds__(256) void fsi_kernel(const float* __restrict__ f_proj,
                                                  const float* __restrict__ hmag,
                                                  float* __restrict__ fsi_out) {
  int tok = blockIdx.x * 4 + (threadIdx.x >> 6);
  int l = threadIdx.x & 63;
  float2 v = *(const float2*)&f_proj[(size_t)tok * DI_ + l * 2];
  float s = v.x * v.x + v.y * v.y;
#pragma unroll
  for (int o = 32; o; o >>= 1) s += __shfl_down(s, o);
  if (l == 0) fsi_out[tok] = hmag[tok] / (2.f * sqrtf(s) + 1e-6f);
}

// ---------------- launcher ----------------
extern "C" void kernel_launch(void* const* d_in, const int* in_sizes, int n_in,
                              void* d_out, int out_size, void* d_ws, size_t ws_size,
                              hipStream_t stream) {
  (void)in_sizes; (void)n_in; (void)out_size; (void)ws_size;
  const float* h = (const float*)d_in[0];
  const float* ln_w = (const float*)d_in[1];
  const float* ln_b = (const float*)d_in[2];
  const float* w_q = (const float*)d_in[3];
  const float* w_k = (const float*)d_in[4];
  const float* w_v = (const float*)d_in[5];
  const float* w_o = (const float*)d_in[6];
  const float* b_o = (const float*)d_in[7];
  const float* U = (const float*)d_in[8];
  const float* V = (const float*)d_in[9];
  const float* gamma_w = (const float*)d_in[10];
  const float* gamma_b = (const float*)d_in[11];
  const float* mass_w = (const float*)d_in[12];
  const float* mass_b = (const float*)d_in[13];
  const float* eps_w = (const float*)d_in[14];
  const float* eps_b = (const float*)d_in[15];
  const float* lg_w1 = (const float*)d_in[16];
  const float* lg_b1 = (const float*)d_in[17];
  const float* lg_w2 = (const float*)d_in[18];
  const float* lg_b2 = (const float*)d_in[19];
  const float* mlp_w1 = (const float*)d_in[20];
  const float* mlp_b1 = (const float*)d_in[21];
  const float* mlp_w2 = (const float*)d_in[22];
  const float* mlp_b2 = (const float*)d_in[23];

  float* out_h = (float*)d_out;
  float* out_m = out_h + (size_t)NTOK * C_;
  float* out_fsi = out_m + (size_t)NTOK * DI_;

  char* wsb = (char*)d_ws;
  size_t off = 0;
  auto al = [&](size_t bytes) {
    void* p = wsb + off;
    off += (bytes + 255) & ~(size_t)255;
    return p;
  };
  short* wqkvt = (short*)al((size_t)C3 * C_ * 2);
  short* wot = (short*)al((size_t)C_ * C_ * 2);
  short* ut = (short*)al((size_t)DI_ * C_ * 2);
  short* vt = (short*)al((size_t)C_ * DI_ * 2);
  short* lg1t = (short*)al((size_t)C4 * C_ * 2);
  short* lg2t = (short*)al((size_t)C_ * C4 * 2);
  short* mlp1t = (short*)al((size_t)C4 * C_ * 2);
  short* mlp2t = (short*)al((size_t)C_ * C4 * 2);
  float* h_norm = (float*)al((size_t)NTOK * C_ * 4);
  short* hn_bf = (short*)al((size_t)NTOK * C_ * 2);
  short* qkv_bf = (short*)al((size_t)NTOK * C3 * 2);
  short* tmp_bf = (short*)al((size_t)NTOK * C_ * 2);
  float* f_proj = (float*)al((size_t)NTOK * DI_ * 4);
  short* act = (short*)al((size_t)NTOK * C4 * 2);
  float* h_pre = (float*)al((size_t)NTOK * C_ * 4);
  short* vtrans = (short*)al((size_t)B_ * H_ * 64 * T_ * 2);
  float* gammaA = (float*)al((size_t)NTOK * 4);
  float* epsA = (float*)al((size_t)NTOK * 4);
  float* massA = (float*)al((size_t)NTOK * 4);
  float* coefA = (float*)al((size_t)NTOK * 4);
  float* hmagA = (float*)al((size_t)NTOK * 4);
  short* ftot_bf = hn_bf;
  short* m_bf = act;
  float* h_new = (float*)qkv_bf;

  dim3 blk(256);
  transpose_cvt<<<dim3(C_ / 32, C_ / 32), blk, 0, stream>>>(w_q, wqkvt, C_, C_);
  transpose_cvt<<<dim3(C_ / 32, C_ / 32), blk, 0, stream>>>(w_k, wqkvt + (size_t)C_ * C_, C_, C_);
  transpose_cvt<<<dim3(C_ / 32, C_ / 32), blk, 0, stream>>>(w_v, wqkvt + (size_t)2 * C_ * C_, C_, C_);
  transpose_cvt<<<dim3(C_ / 32, C_ / 32), blk, 0, stream>>>(w_o, wot, C_, C_);
  transpose_cvt<<<dim3(DI_ / 32, C_ / 32), blk, 0, stream>>>(U, ut, C_, DI_);
  transpose_cvt<<<dim3(C_ / 32, DI_ / 32), blk, 0, stream>>>(V, vt, DI_, C_);
  transpose_cvt<<<dim3(C4 / 32, C_ / 32), blk, 0, stream>>>(lg_w1, lg1t, C_, C4);
  transpose_cvt<<<dim3(C_ / 32, C4 / 32), blk, 0, stream>>>(lg_w2, lg2t, C4, C_);
  transpose_cvt<<<dim3(C4 / 32, C_ / 32), blk, 0, stream>>>(mlp_w1, mlp1t, C_, C4);
  transpose_cvt<<<dim3(C_ / 32, C4 / 32), blk, 0, stream>>>(mlp_w2, mlp2t, C4, C_);

  ln_kernel<1, 1><<<NTOK, blk, 0, stream>>>(h, ln_w, ln_b, h_norm, hn_bf, gamma_w, gamma_b,
                                            mass_w, mass_b, eps_w, eps_b, gammaA, epsA, massA,
                                            coefA, hmagA);
  // fused QKV: wide-K, grid 768
  gemmW<1, 0><<<(NTOK / 128) * (C3 / 128), blk, 0, stream>>>(hn_bf, wqkvt, qkv_bf, nullptr,
                                                             nullptr, nullptr, NTOK, C3, C_);
  transpose_v<<<dim3(T_ / 32, 2, B_ * H_), blk, 0, stream>>>(qkv_bf, vtrans);
  attn_kernel<<<dim3(T_ / 64, B_ * H_), blk, 0, stream>>>(qkv_bf, vtrans, tmp_bf);
  // wo: 64x64, grid 1024
  gemmS64<2><<<(NTOK / 64) * (C_ / 64), blk, 0, stream>>>(tmp_bf, wot, ftot_bf, b_o,
                                                          h_norm, nullptr, NTOK, C_, C_);
  // U: 64x64, grid 128
  gemmS64<0><<<(NTOK / 64) * (DI_ / 64), blk, 0, stream>>>(ftot_bf, ut, f_proj, nullptr,
                                                           nullptr, nullptr, NTOK, DI_, C_);
  fsi_kernel<<<NTOK / 4, blk, 0, stream>>>(f_proj, hmagA, out_fsi);
  scan_kernel<<<B_, dim3(DI_), 0, stream>>>(f_proj, gammaA, coefA, out_m, m_bf);
  // V-gemm: 64x64, grid 1024 (K=128)
  gemmS64<3><<<(NTOK / 64) * (C_ / 64), blk, 0, stream>>>(m_bf, vt, h_new, nullptr, h,
                                                          epsA, NTOK, C_, DI_);
  ln_kernel<0, 0><<<NTOK, blk, 0, stream>>>(h_new, ln_w, ln_b, nullptr, tmp_bf, nullptr, nullptr,
                                            nullptr, nullptr, nullptr, nullptr, nullptr, nullptr,
                                            nullptr, nullptr, nullptr);
  // lg1: wide-K, grid 1024
  gemmW<4, 0><<<(NTOK / 128) * (C4 / 128), blk, 0, stream>>>(tmp_bf, lg1t, act, lg_b1,
                                                             nullptr, nullptr, NTOK, C4, C_);
  // lg2: 64x64, grid 1024
  gemmS64<5><<<(NTOK / 64) * (C_ / 64), blk, 0, stream>>>(act, lg2t, h_pre, lg_b2,
                                                          h_new, massA, NTOK, C_, C4);
  ln_kernel<0, 0><<<NTOK, blk, 0, stream>>>(h_pre, ln_w, ln_b, nullptr, tmp_bf, nullptr, nullptr,
                                            nullptr, nullptr, nullptr, nullptr, nullptr, nullptr,
                                            nullptr, nullptr, nullptr);
  gemmW<4, 0><<<(NTOK / 128) * (C4 / 128), blk, 0, stream>>>(tmp_bf, mlp1t, act, mlp_b1,
                                                             nullptr, nullptr, NTOK, C4, C_);
  gemmS64<6><<<(NTOK / 64) * (C_ / 64), blk, 0, stream>>>(act, mlp2t, out_h, mlp_b2,
                                                          h_pre, nullptr, NTOK, C_, C4);
}